// Round 2
// baseline (85.471 us; speedup 1.0000x reference)
//
#include <hip/hip_runtime.h>

// Nearest-neighbor scatter-to-grid:
//   for each batch b, grid cell g: idx = argmin_n (||p_n||^2 - 2 * g . p_n)
//   out[b,c,g] = R[b,c,idx]
// H = W = 256, N = 1024, C = 4, B = 2 (derived defensively from in_sizes).
//
// Correctness: must reproduce XLA:CPU f32 rounding bitwise in near-tie cells:
//  - pp  = round(px*px) + round(py*py)           (XLA fused mul+reduce, no FMA)
//  - dot = fma(gy, py, round(gx*px))             (Eigen gemm: sequential FMA, k asc.)
//  - d2  = round(pp - 2*dot)                     (2*dot exact; single rounding)
//  - argmin: strict '<' ascending scan = first-occurrence tie-break (jnp.argmin)

#define GRID_H 256
#define GRID_W 256
#define GRID_G (GRID_H * GRID_W)
#define NPTS   1024
#define BLOCK  256

__global__ __launch_bounds__(BLOCK) void nn_grid_gather_kernel(
    const float* __restrict__ R,    // [B, C, N]
    const float* __restrict__ XY,   // [B, 2, N]
    float*       __restrict__ out,  // [B, C, H, W]
    int B, int C, int N)
{
#pragma clang fp contract(off)
    __shared__ float4 pts[NPTS];  // {px, py, px*px+py*py, unused}

    const int blocksPerBatch = GRID_G / BLOCK;          // 256
    const int b = blockIdx.x / blocksPerBatch;
    const int g = (blockIdx.x % blocksPerBatch) * BLOCK + threadIdx.x;

    // Stage points for this batch into LDS (each thread loads N/BLOCK = 4).
    const float* xb = XY + (size_t)b * 2 * N;
    for (int i = threadIdx.x; i < N; i += BLOCK) {
        float px = xb[i];
        float py = xb[N + i];
        float pp = px * px + py * py;   // contract(off): mul, mul, add (matches XLA reduce)
        pts[i] = make_float4(px, py, pp, 0.0f);
    }
    __syncthreads();

    const int x = g & (GRID_W - 1);
    const int y = g >> 8;
    // (x + 0.5) / 256 is exact in f32; multiply by exact 2^-8 is identical.
    const float gx = ((float)x + 0.5f) * (1.0f / GRID_W);
    const float gy = ((float)y + 0.5f) * (1.0f / GRID_H);

    float best = 3.4e38f;
    int   bi   = 0;
    #pragma unroll 8
    for (int n = 0; n < NPTS; ++n) {
        float4 p  = pts[n];                  // wave-uniform address -> broadcast
        // Eigen gemm rounding: t = round(gx*px); dot = fma(gy, py, t)
        float  dot = fmaf(gy, p.y, gx * p.x);
        // pp - 2*dot: 2*dot exact (exponent bump) -> fmaf is bitwise identical
        // to the reference's round(pp - 2*dot).
        float  d2 = fmaf(-2.0f, dot, p.z);
        if (d2 < best) { best = d2; bi = n; }   // strict '<': first-occurrence ties
    }

    // Gather C channel values for the winning point; coalesced stores per c.
    const float* rb = R + (size_t)b * C * N;
    float*       ob = out + (size_t)b * C * GRID_G;
    for (int c = 0; c < C; ++c) {
        ob[(size_t)c * GRID_G + g] = rb[(size_t)c * N + bi];
    }
}

extern "C" void kernel_launch(void* const* d_in, const int* in_sizes, int n_in,
                              void* d_out, int out_size, void* d_ws, size_t ws_size,
                              hipStream_t stream) {
    const float* R  = (const float*)d_in[0];   // [B, C, N] f32
    const float* XY = (const float*)d_in[1];   // [B, 2, N] f32
    float* out = (float*)d_out;                // [B, C, H, W] f32

    const int N = NPTS;
    const int B = in_sizes[1] / (2 * N);       // 4096 / 2048 = 2
    const int C = in_sizes[0] / (B * N);       // 8192 / 2048 = 4

    const int nblocks = B * (GRID_G / BLOCK);  // 2 * 256 = 512
    nn_grid_gather_kernel<<<nblocks, BLOCK, 0, stream>>>(R, XY, out, B, C, N);
}